// Round 1
// baseline (538.539 us; speedup 1.0000x reference)
//
#include <hip/hip_runtime.h>

#define BB 16
#define CC 3
#define HH 512
#define WW 512
#define HWP (HH*WW)
#define NMAP (BB*HWP)

// ---------------------------------------------------------------------------
// s = sum_c x_c ; q = sum_c x_c^2   (per pixel, channel-collapsed moments)
// ---------------------------------------------------------------------------
__global__ void init_sq(const float* __restrict__ x, float* __restrict__ s,
                        float* __restrict__ q) {
    int i = blockIdx.x * 256 + threadIdx.x;          // over B*H*W (exact)
    int b = i / HWP, p = i - b * HWP;
    const float* xb = x + (size_t)b * CC * HWP + p;
    float x0 = xb[0], x1 = xb[HWP], x2 = xb[2 * HWP];
    s[i] = x0 + x1 + x2;
    q[i] = x0 * x0 + x1 * x1 + x2 * x2;
}

// ---------------------------------------------------------------------------
// Horizontal box pass (zero-pad "same"), processes a PAIR of maps via grid.y.
// One block per image row; row staged in LDS.
// ---------------------------------------------------------------------------
template <int PAD>
__global__ void hpass(const float* __restrict__ in0, float* __restrict__ out0,
                      const float* __restrict__ in1, float* __restrict__ out1) {
    __shared__ float row[WW];
    const float* in = blockIdx.y ? in1 : in0;
    float* out = blockIdx.y ? out1 : out0;
    size_t base = (size_t)blockIdx.x * WW;           // blockIdx.x in [0, B*H)
    int t = threadIdx.x;
    row[t] = in[base + t];
    row[t + 256] = in[base + t + 256];
    __syncthreads();
#pragma unroll
    for (int j = 0; j < 2; ++j) {
        int w = t + j * 256;
        int lo = w - PAD; if (lo < 0) lo = 0;
        int hi = w + PAD; if (hi > WW - 1) hi = WW - 1;
        float sum = 0.f;
        for (int u = lo; u <= hi; ++u) sum += row[u];
        out[base + w] = sum;
    }
}

// ---------------------------------------------------------------------------
// Vertical box pass (zero-pad "same"), pair of maps via grid.y. Coalesced in w.
// ---------------------------------------------------------------------------
template <int PAD>
__global__ void vpass(const float* __restrict__ in0, float* __restrict__ out0,
                      const float* __restrict__ in1, float* __restrict__ out1) {
    int i = blockIdx.x * 256 + threadIdx.x;          // over B*H*W (exact)
    const float* in = blockIdx.y ? in1 : in0;
    float* out = blockIdx.y ? out1 : out0;
    int b = i / HWP, p = i - b * HWP;
    int h = p / WW, w = p - h * WW;
    const float* col = in + (size_t)b * HWP + w;
    int lo = h - PAD; if (lo < 0) lo = 0;
    int hi = h + PAD; if (hi > HH - 1) hi = HH - 1;
    float sum = 0.f;
    for (int u = lo; u <= hi; ++u) sum += col[u * WW];
    out[i] = sum;
}

// ---------------------------------------------------------------------------
// Per-pixel A / b from box-summed moments. In-place: S<-A, Q<-b.
// Nc = 3 * window_count (analytic, matches box of ones with zero pad).
// ---------------------------------------------------------------------------
__global__ void pointAb(float* __restrict__ S, float* __restrict__ Q,
                        float eps, int pad) {
    int i = blockIdx.x * 256 + threadIdx.x;
    int p = i % HWP;
    int h = p / WW, w = p - h * WW;
    int hlo = h - pad; if (hlo < 0) hlo = 0;
    int hhi = h + pad; if (hhi > HH - 1) hhi = HH - 1;
    int wlo = w - pad; if (wlo < 0) wlo = 0;
    int whi = w + pad; if (whi > WW - 1) whi = WW - 1;
    float Nc = 3.f * (float)((hhi - hlo + 1) * (whi - wlo + 1));
    float mean = S[i] / Nc;
    float var = Q[i] / Nc - mean * mean;
    float A = var / (var + eps);
    S[i] = A;
    Q[i] = mean * (1.f - A);
}

// ---------------------------------------------------------------------------
// Moment update for the next stage: F_c = mA*x_c + mb (mA = 3*raw box of A).
//   s' = mA*s + 3*mb ; q' = mA^2 q + 2 mA mb s + 3 mb^2
// ---------------------------------------------------------------------------
__global__ void updateSQ(const float* __restrict__ mAr, const float* __restrict__ mbr,
                         float* __restrict__ s, float* __restrict__ q) {
    int i = blockIdx.x * 256 + threadIdx.x;
    float mA = 3.f * mAr[i], mb = 3.f * mbr[i];
    float sv = s[i], qv = q[i];
    s[i] = mA * sv + 3.f * mb;
    q[i] = mA * mA * qv + 2.f * mA * mb * sv + 3.f * mb * mb;
}

// ---------------------------------------------------------------------------
// Epilogue: F_g = P_g*x + Q_g per pixel (affine in x), D groups are
// (P_{g-1}-P_g)*x + (Q_{g-1}-Q_g); fold the 1x1 conv (w1: 3x9) directly.
// ---------------------------------------------------------------------------
__global__ void finalk(const float* __restrict__ x, const float* __restrict__ w1,
                       const float* __restrict__ mA1, const float* __restrict__ mb1,
                       const float* __restrict__ mA2, const float* __restrict__ mb2,
                       const float* __restrict__ mA3, const float* __restrict__ mb3,
                       float* __restrict__ out) {
    int i = blockIdx.x * 256 + threadIdx.x;          // over B*H*W
    int b = i / HWP, p = i - b * HWP;
    float A1 = 3.f * mA1[i], B1 = 3.f * mb1[i];
    float A2 = 3.f * mA2[i], B2 = 3.f * mb2[i];
    float A3 = 3.f * mA3[i], B3 = 3.f * mb3[i];
    float P1 = A1,       Q1 = B1;
    float P2 = A2 * P1,  Q2 = A2 * Q1 + B2;
    float P3 = A3 * P2,  Q3 = A3 * Q2 + B3;
    float alpha[3] = {1.f - P1, P1 - P2, P2 - P3};
    float beta[3]  = {-Q1,      Q1 - Q2, Q2 - Q3};
    const float* xb = x + (size_t)b * CC * HWP + p;
    float x0 = xb[0], x1 = xb[HWP], x2 = xb[2 * HWP];
#pragma unroll
    for (int o = 0; o < 3; ++o) {
        float acc = 0.f;
#pragma unroll
        for (int g = 0; g < 3; ++g) {
            float w0 = w1[o * 9 + g * 3 + 0];
            float w1v = w1[o * 9 + g * 3 + 1];
            float w2 = w1[o * 9 + g * 3 + 2];
            acc += alpha[g] * (w0 * x0 + w1v * x1 + w2 * x2)
                 + beta[g] * (w0 + w1v + w2);
        }
        out[(size_t)(b * 3 + o) * HWP + p] = acc;
    }
}

extern "C" void kernel_launch(void* const* d_in, const int* in_sizes, int n_in,
                              void* d_out, int out_size, void* d_ws, size_t ws_size,
                              hipStream_t stream) {
    (void)in_sizes; (void)n_in; (void)out_size; (void)ws_size;
    const float* x  = (const float*)d_in[0];
    const float* w1 = (const float*)d_in[1];
    float* out = (float*)d_out;
    float* ws = (float*)d_ws;

    // 10 maps of B*H*W floats = 167.8 MB workspace
    float* s   = ws + 0ull * NMAP;
    float* q   = ws + 1ull * NMAP;
    float* t0  = ws + 2ull * NMAP;
    float* t1  = ws + 3ull * NMAP;
    float* mA1 = ws + 4ull * NMAP;
    float* mb1 = ws + 5ull * NMAP;
    float* mA2 = ws + 6ull * NMAP;
    float* mb2 = ws + 7ull * NMAP;
    float* mA3 = ws + 8ull * NMAP;   // doubles as hpass temp until stage-3 end
    float* mb3 = ws + 9ull * NMAP;   // doubles as hpass temp until stage-3 end

    dim3 bl(256);
    dim3 gP(NMAP / 256);
    dim3 gH(BB * HH, 2);
    dim3 gV(NMAP / 256, 2);

    init_sq<<<gP, bl, 0, stream>>>(x, s, q);

    // -------- stage 1: k=3 (PAD=1), eps=0.16 --------
    hpass<1><<<gH, bl, 0, stream>>>(s, mA3, q, mb3);
    vpass<1><<<gV, bl, 0, stream>>>(mA3, t0, mb3, t1);
    pointAb<<<gP, bl, 0, stream>>>(t0, t1, 0.16f, 1);
    hpass<1><<<gH, bl, 0, stream>>>(t0, mA3, t1, mb3);
    vpass<1><<<gV, bl, 0, stream>>>(mA3, mA1, mb3, mb1);
    updateSQ<<<gP, bl, 0, stream>>>(mA1, mb1, s, q);

    // -------- stage 2: k=7 (PAD=3), eps=0.04 --------
    hpass<3><<<gH, bl, 0, stream>>>(s, mA3, q, mb3);
    vpass<3><<<gV, bl, 0, stream>>>(mA3, t0, mb3, t1);
    pointAb<<<gP, bl, 0, stream>>>(t0, t1, 0.04f, 3);
    hpass<3><<<gH, bl, 0, stream>>>(t0, mA3, t1, mb3);
    vpass<3><<<gV, bl, 0, stream>>>(mA3, mA2, mb3, mb2);
    updateSQ<<<gP, bl, 0, stream>>>(mA2, mb2, s, q);

    // -------- stage 3: k=15 (PAD=7), eps=0.01 --------
    hpass<7><<<gH, bl, 0, stream>>>(s, mA3, q, mb3);   // mA3/mb3 still free
    vpass<7><<<gV, bl, 0, stream>>>(mA3, t0, mb3, t1);
    pointAb<<<gP, bl, 0, stream>>>(t0, t1, 0.01f, 7);
    hpass<7><<<gH, bl, 0, stream>>>(t0, s, t1, q);     // s,q dead after this stage
    vpass<7><<<gV, bl, 0, stream>>>(s, mA3, q, mb3);   // final mA3, mb3

    finalk<<<gP, bl, 0, stream>>>(x, w1, mA1, mb1, mA2, mb2, mA3, mb3, out);
}

// Round 2
// 404.827 us; speedup vs baseline: 1.3303x; 1.3303x over previous
//
#include <hip/hip_runtime.h>

#define BB 16
#define CC 3
#define HH 512
#define WW 512
#define HWP (HH*WW)
#define NMAP (BB*HWP)

// ---------------------------------------------------------------------------
// s = sum_c x_c ; q = sum_c x_c^2   (per pixel, channel-collapsed moments)
// ---------------------------------------------------------------------------
__global__ void init_sq(const float* __restrict__ x, float* __restrict__ s,
                        float* __restrict__ q) {
    int i = blockIdx.x * 256 + threadIdx.x;          // over B*H*W (exact)
    int b = i / HWP, p = i - b * HWP;
    const float* xb = x + (size_t)b * CC * HWP + p;
    float x0 = xb[0], x1 = xb[HWP], x2 = xb[2 * HWP];
    s[i] = x0 + x1 + x2;
    q[i] = x0 * x0 + x1 * x1 + x2 * x2;
}

// ---------------------------------------------------------------------------
// Fused 2D box filter (zero-pad "same") of a PAIR of maps, streaming down h
// with a running column sum. Each thread owns one column (w); the horizontal
// sum of each incoming row is computed from global (L1-served, neighbors share
// lines) and pushed into a per-thread LDS ring (size 2P+2, pow2) so it can be
// subtracted when it leaves the vertical window. No __syncthreads needed:
// ring slots are thread-private. MODE 0: emit A,b (guided-filter pointwise).
// MODE 1: emit raw box pair AND update s,q moments in place.
// MODE 2: emit raw box pair only.
// ---------------------------------------------------------------------------
template <int PAD, int CH, int MODE>
__global__ void fusedbox(const float* __restrict__ in0, const float* __restrict__ in1,
                         float* __restrict__ out0, float* __restrict__ out1,
                         float* __restrict__ sm, float* __restrict__ qm,
                         float eps) {
    constexpr int RING = 2 * PAD + 2;                // 4 / 8 / 16 — all pow2
    __shared__ float ring0[RING][256];
    __shared__ float ring1[RING][256];
    constexpr int NCH = HH / CH;

    int bx = blockIdx.x;
    int chunk = bx % NCH;
    int strip = (bx / NCH) & 1;                      // 512 = 2 strips of 256
    int b = bx / (NCH * 2);
    int t = threadIdx.x;
    int w = strip * 256 + t;
    size_t mapbase = (size_t)b * HWP;
    const float* p0 = in0 + mapbase;
    const float* p1 = in1 + mapbase;

    int h0 = chunk * CH;
    int wlo = (w - PAD < 0) ? 0 : w - PAD;
    int whi = (w + PAD > WW - 1) ? WW - 1 : w + PAD;
    float cs0 = 0.f, cs1 = 0.f;

    for (int hin = h0 - PAD; hin < h0 + CH + PAD; ++hin) {
        float hs0 = 0.f, hs1 = 0.f;
        if ((unsigned)hin < (unsigned)HH) {
            const float* r0 = p0 + (size_t)hin * WW;
            const float* r1 = p1 + (size_t)hin * WW;
#pragma unroll
            for (int d = -PAD; d <= PAD; ++d) {
                int wc = w + d;
                if ((unsigned)wc < (unsigned)WW) {
                    hs0 += r0[wc];
                    hs1 += r1[wc];
                }
            }
        }
        int slot = (hin + 1024) & (RING - 1);
        ring0[slot][t] = hs0;
        ring1[slot][t] = hs1;
        cs0 += hs0;
        cs1 += hs1;

        int ho = hin - PAD;
        if (ho >= h0) {
            size_t oi = mapbase + (size_t)ho * WW + w;
            if (MODE == 0) {
                int hlo = (ho - PAD < 0) ? 0 : ho - PAD;
                int hhi = (ho + PAD > HH - 1) ? HH - 1 : ho + PAD;
                float Nc = 3.f * (float)((hhi - hlo + 1) * (whi - wlo + 1));
                float mean = cs0 / Nc;
                float var = cs1 / Nc - mean * mean;
                float A = var / (var + eps);
                out0[oi] = A;
                out1[oi] = mean * (1.f - A);
            } else {
                out0[oi] = cs0;                      // raw box sums; final/update scale by 3
                out1[oi] = cs1;
                if (MODE == 1) {
                    float mA = 3.f * cs0, mb = 3.f * cs1;
                    float sv = sm[oi], qv = qm[oi];
                    sm[oi] = mA * sv + 3.f * mb;
                    qm[oi] = mA * mA * qv + 2.f * mA * mb * sv + 3.f * mb * mb;
                }
            }
            int old = (ho - PAD + 1024) & (RING - 1);
            cs0 -= ring0[old][t];
            cs1 -= ring1[old][t];
        }
    }
}

// ---------------------------------------------------------------------------
// Epilogue: F_g = P_g*x + Q_g per pixel (affine in x), D groups are
// (P_{g-1}-P_g)*x + (Q_{g-1}-Q_g); fold the 1x1 conv (w1: 3x9) directly.
// mA*/mb* hold RAW box sums (scale by 3 here = weight-1 conv channel sum).
// ---------------------------------------------------------------------------
__global__ void finalk(const float* __restrict__ x, const float* __restrict__ w1,
                       const float* __restrict__ mA1, const float* __restrict__ mb1,
                       const float* __restrict__ mA2, const float* __restrict__ mb2,
                       const float* __restrict__ mA3, const float* __restrict__ mb3,
                       float* __restrict__ out) {
    int i = blockIdx.x * 256 + threadIdx.x;          // over B*H*W
    int b = i / HWP, p = i - b * HWP;
    float A1 = 3.f * mA1[i], B1 = 3.f * mb1[i];
    float A2 = 3.f * mA2[i], B2 = 3.f * mb2[i];
    float A3 = 3.f * mA3[i], B3 = 3.f * mb3[i];
    float P1 = A1,       Q1 = B1;
    float P2 = A2 * P1,  Q2 = A2 * Q1 + B2;
    float P3 = A3 * P2,  Q3 = A3 * Q2 + B3;
    float alpha[3] = {1.f - P1, P1 - P2, P2 - P3};
    float beta[3]  = {-Q1,      Q1 - Q2, Q2 - Q3};
    const float* xb = x + (size_t)b * CC * HWP + p;
    float x0 = xb[0], x1 = xb[HWP], x2 = xb[2 * HWP];
#pragma unroll
    for (int o = 0; o < 3; ++o) {
        float acc = 0.f;
#pragma unroll
        for (int g = 0; g < 3; ++g) {
            float w0 = w1[o * 9 + g * 3 + 0];
            float w1v = w1[o * 9 + g * 3 + 1];
            float w2 = w1[o * 9 + g * 3 + 2];
            acc += alpha[g] * (w0 * x0 + w1v * x1 + w2 * x2)
                 + beta[g] * (w0 + w1v + w2);
        }
        out[(size_t)(b * 3 + o) * HWP + p] = acc;
    }
}

extern "C" void kernel_launch(void* const* d_in, const int* in_sizes, int n_in,
                              void* d_out, int out_size, void* d_ws, size_t ws_size,
                              hipStream_t stream) {
    (void)in_sizes; (void)n_in; (void)out_size; (void)ws_size;
    const float* x  = (const float*)d_in[0];
    const float* w1 = (const float*)d_in[1];
    float* out = (float*)d_out;
    float* ws = (float*)d_ws;

    // 10 maps of B*H*W floats = 167.8 MB workspace
    float* s   = ws + 0ull * NMAP;
    float* q   = ws + 1ull * NMAP;
    float* tA  = ws + 2ull * NMAP;
    float* tb  = ws + 3ull * NMAP;
    float* mA1 = ws + 4ull * NMAP;
    float* mb1 = ws + 5ull * NMAP;
    float* mA2 = ws + 6ull * NMAP;
    float* mb2 = ws + 7ull * NMAP;
    float* mA3 = ws + 8ull * NMAP;
    float* mb3 = ws + 9ull * NMAP;

    dim3 bl(256);
    dim3 gP(NMAP / 256);
    // grid = B * 2 strips * (HH/CH) chunks
    dim3 g16(BB * 2 * (HH / 16));                    // PAD=1: CH=16 -> 1024 blocks
    dim3 g32(BB * 2 * (HH / 32));                    // PAD=3,7: CH=32 -> 512 blocks

    init_sq<<<gP, bl, 0, stream>>>(x, s, q);

    // -------- stage 1: k=3 (PAD=1), eps=0.16 --------
    fusedbox<1, 16, 0><<<g16, bl, 0, stream>>>(s, q, tA, tb, s, q, 0.16f);
    fusedbox<1, 16, 1><<<g16, bl, 0, stream>>>(tA, tb, mA1, mb1, s, q, 0.f);

    // -------- stage 2: k=7 (PAD=3), eps=0.04 --------
    fusedbox<3, 32, 0><<<g32, bl, 0, stream>>>(s, q, tA, tb, s, q, 0.04f);
    fusedbox<3, 32, 1><<<g32, bl, 0, stream>>>(tA, tb, mA2, mb2, s, q, 0.f);

    // -------- stage 3: k=15 (PAD=7), eps=0.01 --------
    fusedbox<7, 32, 0><<<g32, bl, 0, stream>>>(s, q, tA, tb, s, q, 0.01f);
    fusedbox<7, 32, 2><<<g32, bl, 0, stream>>>(tA, tb, mA3, mb3, s, q, 0.f);

    finalk<<<gP, bl, 0, stream>>>(x, w1, mA1, mb1, mA2, mb2, mA3, mb3, out);
}

// Round 3
// 264.147 us; speedup vs baseline: 2.0388x; 1.5326x over previous
//
#include <hip/hip_runtime.h>

#define BB 16
#define CC 3
#define HH 512
#define WW 512
#define HWP (HH*WW)
#define NMAP (BB*HWP)

// ---------------------------------------------------------------------------
// s = sum_c x_c ; q = sum_c x_c^2  — float4 vectorized
// ---------------------------------------------------------------------------
__global__ void init_sq(const float* __restrict__ x, float* __restrict__ s,
                        float* __restrict__ q) {
    int i = blockIdx.x * 256 + threadIdx.x;          // over NMAP/4
    int b = i / (HWP / 4), p = i - b * (HWP / 4);
    const float4* xb = (const float4*)(x + (size_t)b * CC * HWP) + p;
    float4 a0 = xb[0], a1 = xb[HWP / 4], a2 = xb[2 * (HWP / 4)];
    float4 sv, qv;
    sv.x = a0.x + a1.x + a2.x; qv.x = a0.x * a0.x + a1.x * a1.x + a2.x * a2.x;
    sv.y = a0.y + a1.y + a2.y; qv.y = a0.y * a0.y + a1.y * a1.y + a2.y * a2.y;
    sv.z = a0.z + a1.z + a2.z; qv.z = a0.z * a0.z + a1.z * a1.z + a2.z * a2.z;
    sv.w = a0.w + a1.w + a2.w; qv.w = a0.w * a0.w + a1.w * a1.w + a2.w * a2.w;
    ((float4*)s)[i] = sv;
    ((float4*)q)[i] = qv;
}

// ---------------------------------------------------------------------------
// Fused 2D box filter of a PAIR of maps, vertical-first.
// Each thread owns one column: running column sum cs += row(h+P) - row(h-P-1)
// (old row re-loaded from global -> L1/L2 hit). Colsums exchanged through a
// double-buffered LDS row so each lane sums 2P+1 stride-1 neighbors (no bank
// conflicts, one __syncthreads per row). First/last P threads additionally
// maintain a halo column. MODE 0: emit A,b. MODE 1: emit box pair + update
// s,q moments in place. MODE 2: emit box pair.
// ---------------------------------------------------------------------------
template <int PAD, int CH, int MODE>
__global__ void fusedbox(const float* __restrict__ in0, const float* __restrict__ in1,
                         float* __restrict__ out0, float* __restrict__ out1,
                         float* __restrict__ sm, float* __restrict__ qm,
                         float eps) {
    constexpr int HW = 256 + 2 * PAD;
    __shared__ float hr[2][2][HW];
    constexpr int NCH = HH / CH;

    int bx = blockIdx.x;
    int chunk = bx % NCH;
    int strip = (bx / NCH) & 1;
    int b = bx / (NCH * 2);
    int t = threadIdx.x;
    int w0 = strip * 256;
    int w = w0 + t;
    size_t mapbase = (size_t)b * HWP;
    const float* p0 = in0 + mapbase;
    const float* p1 = in1 + mapbase;

    // halo column handled by this thread (if any)
    bool halo = (t < PAD) || (t >= 256 - PAD);
    int hcol = (t < PAD) ? (w0 - PAD + t) : (w0 + PAD + t);
    int hoff = (t < PAD) ? t : (t + 2 * PAD);
    bool hvalid = halo && ((unsigned)hcol < (unsigned)WW);

    int h0 = chunk * CH;
    float cs0 = 0.f, cs1 = 0.f, hc0 = 0.f, hc1 = 0.f;
    // prime: rows h0-P .. h0+P
    for (int r = h0 - PAD; r <= h0 + PAD; ++r) {
        if ((unsigned)r < (unsigned)HH) {
            size_t ro = (size_t)r * WW;
            cs0 += p0[ro + w];
            cs1 += p1[ro + w];
            if (hvalid) { hc0 += p0[ro + hcol]; hc1 += p1[ro + hcol]; }
        }
    }

    int wlo = (w - PAD < 0) ? 0 : w - PAD;
    int whi = (w + PAD > WW - 1) ? WW - 1 : w + PAD;

    for (int h = h0; h < h0 + CH; ++h) {
        int buf = h & 1;
        hr[buf][0][t + PAD] = cs0;
        hr[buf][1][t + PAD] = cs1;
        if (halo) {
            hr[buf][0][hoff] = hvalid ? hc0 : 0.f;
            hr[buf][1][hoff] = hvalid ? hc1 : 0.f;
        }
        __syncthreads();
        float hs0 = 0.f, hs1 = 0.f;
#pragma unroll
        for (int d = 0; d <= 2 * PAD; ++d) {
            hs0 += hr[buf][0][t + d];
            hs1 += hr[buf][1][t + d];
        }
        size_t oi = mapbase + (size_t)h * WW + w;
        if (MODE == 0) {
            int hlo = (h - PAD < 0) ? 0 : h - PAD;
            int hhi = (h + PAD > HH - 1) ? HH - 1 : h + PAD;
            float Nc = 3.f * (float)((hhi - hlo + 1) * (whi - wlo + 1));
            float mean = hs0 / Nc;
            float var = hs1 / Nc - mean * mean;
            float A = var / (var + eps);
            out0[oi] = A;
            out1[oi] = mean * (1.f - A);
        } else {
            out0[oi] = hs0;
            out1[oi] = hs1;
            if (MODE == 1) {
                float mA = 3.f * hs0, mb = 3.f * hs1;
                float sv = sm[oi], qv = qm[oi];
                sm[oi] = mA * sv + 3.f * mb;
                qm[oi] = mA * mA * qv + 2.f * mA * mb * sv + 3.f * mb * mb;
            }
        }
        // advance running sums (skip after last row)
        if (h + 1 < h0 + CH) {
            int rin = h + 1 + PAD, rout = h - PAD;
            size_t ri = (size_t)rin * WW, ro = (size_t)rout * WW;
            if (rin < HH) {
                cs0 += p0[ri + w]; cs1 += p1[ri + w];
                if (hvalid) { hc0 += p0[ri + hcol]; hc1 += p1[ri + hcol]; }
            }
            if (rout >= 0) {
                cs0 -= p0[ro + w]; cs1 -= p1[ro + w];
                if (hvalid) { hc0 -= p0[ro + hcol]; hc1 -= p1[ro + hcol]; }
            }
        }
    }
}

// ---------------------------------------------------------------------------
// Epilogue (float4): F_g = P_g*x + Q_g, D = diffs, fold 1x1 conv (w1: 3x9).
// mA*/mb* hold RAW box sums (scale by 3 = weight-1 conv channel sum).
// ---------------------------------------------------------------------------
__global__ void finalk(const float* __restrict__ x, const float* __restrict__ w1,
                       const float* __restrict__ mA1, const float* __restrict__ mb1,
                       const float* __restrict__ mA2, const float* __restrict__ mb2,
                       const float* __restrict__ mA3, const float* __restrict__ mb3,
                       float* __restrict__ out) {
    int i = blockIdx.x * 256 + threadIdx.x;          // over NMAP/4
    int b = i / (HWP / 4), p = i - b * (HWP / 4);
    float4 A1 = ((const float4*)mA1)[i], B1 = ((const float4*)mb1)[i];
    float4 A2 = ((const float4*)mA2)[i], B2 = ((const float4*)mb2)[i];
    float4 A3 = ((const float4*)mA3)[i], B3 = ((const float4*)mb3)[i];
    const float4* xb = (const float4*)(x + (size_t)b * CC * HWP) + p;
    float4 x0 = xb[0], x1 = xb[HWP / 4], x2 = xb[2 * (HWP / 4)];
    float4* ob = (float4*)(out + (size_t)b * CC * HWP) + p;
    float r[3][4];
#pragma unroll
    for (int l = 0; l < 4; ++l) {
        float a1 = 3.f * ((const float*)&A1)[l], b1 = 3.f * ((const float*)&B1)[l];
        float a2 = 3.f * ((const float*)&A2)[l], b2 = 3.f * ((const float*)&B2)[l];
        float a3 = 3.f * ((const float*)&A3)[l], b3 = 3.f * ((const float*)&B3)[l];
        float P1 = a1,      Q1 = b1;
        float P2 = a2 * P1, Q2 = a2 * Q1 + b2;
        float P3 = a3 * P2, Q3 = a3 * Q2 + b3;
        float alpha[3] = {1.f - P1, P1 - P2, P2 - P3};
        float beta[3]  = {-Q1,      Q1 - Q2, Q2 - Q3};
        float xv[3] = {((const float*)&x0)[l], ((const float*)&x1)[l], ((const float*)&x2)[l]};
#pragma unroll
        for (int o = 0; o < 3; ++o) {
            float acc = 0.f;
#pragma unroll
            for (int g = 0; g < 3; ++g) {
                float w0 = w1[o * 9 + g * 3 + 0];
                float w1v = w1[o * 9 + g * 3 + 1];
                float w2 = w1[o * 9 + g * 3 + 2];
                acc += alpha[g] * (w0 * xv[0] + w1v * xv[1] + w2 * xv[2])
                     + beta[g] * (w0 + w1v + w2);
            }
            r[o][l] = acc;
        }
    }
#pragma unroll
    for (int o = 0; o < 3; ++o)
        ob[(size_t)o * (HWP / 4)] = make_float4(r[o][0], r[o][1], r[o][2], r[o][3]);
}

extern "C" void kernel_launch(void* const* d_in, const int* in_sizes, int n_in,
                              void* d_out, int out_size, void* d_ws, size_t ws_size,
                              hipStream_t stream) {
    (void)in_sizes; (void)n_in; (void)out_size; (void)ws_size;
    const float* x  = (const float*)d_in[0];
    const float* w1 = (const float*)d_in[1];
    float* out = (float*)d_out;
    float* ws = (float*)d_ws;

    float* s   = ws + 0ull * NMAP;
    float* q   = ws + 1ull * NMAP;
    float* tA  = ws + 2ull * NMAP;
    float* tb  = ws + 3ull * NMAP;
    float* mA1 = ws + 4ull * NMAP;
    float* mb1 = ws + 5ull * NMAP;
    float* mA2 = ws + 6ull * NMAP;
    float* mb2 = ws + 7ull * NMAP;
    float* mA3 = ws + 8ull * NMAP;
    float* mb3 = ws + 9ull * NMAP;

    dim3 bl(256);
    dim3 gP(NMAP / 256 / 4);
    dim3 g8(BB * 2 * (HH / 8));                      // 2048 blocks
    dim3 g16(BB * 2 * (HH / 16));                    // 1024 blocks

    init_sq<<<gP, bl, 0, stream>>>(x, s, q);

    // -------- stage 1: k=3 (PAD=1), eps=0.16 --------
    fusedbox<1, 8, 0><<<g8, bl, 0, stream>>>(s, q, tA, tb, s, q, 0.16f);
    fusedbox<1, 8, 1><<<g8, bl, 0, stream>>>(tA, tb, mA1, mb1, s, q, 0.f);

    // -------- stage 2: k=7 (PAD=3), eps=0.04 --------
    fusedbox<3, 8, 0><<<g8, bl, 0, stream>>>(s, q, tA, tb, s, q, 0.04f);
    fusedbox<3, 8, 1><<<g8, bl, 0, stream>>>(tA, tb, mA2, mb2, s, q, 0.f);

    // -------- stage 3: k=15 (PAD=7), eps=0.01 --------
    fusedbox<7, 16, 0><<<g16, bl, 0, stream>>>(s, q, tA, tb, s, q, 0.01f);
    fusedbox<7, 16, 2><<<g16, bl, 0, stream>>>(tA, tb, mA3, mb3, s, q, 0.f);

    finalk<<<gP, bl, 0, stream>>>(x, w1, mA1, mb1, mA2, mb2, mA3, mb3, out);
}